// Round 1
// baseline (278.523 us; speedup 1.0000x reference)
//
#include <hip/hip_runtime.h>

#define C0 0.28209479177387814f
#define C1 0.4886025119029199f

__device__ __forceinline__ float sigmoidf(float x) {
    return 1.0f / (1.0f + expf(-x));
}

__global__ __launch_bounds__(256) void gauss_kernel(
    const float* __restrict__ view_dirs,
    const float* __restrict__ xyz,
    const float* __restrict__ scale_log,
    const float4* __restrict__ rot_quat,
    const float* __restrict__ opacity_logit,
    const float4* __restrict__ sh,      // N*3 float4s: [n][channel] -> 4 coeffs
    float* __restrict__ out_xyz,        // N*3
    float* __restrict__ out_cov,        // N*9
    float* __restrict__ out_rgb,        // N*3
    float* __restrict__ out_op,         // N*1
    int N)
{
    int i = blockIdx.x * blockDim.x + threadIdx.x;
    if (i >= N) return;

    // ---- loads ----
    float vx = view_dirs[3*i+0], vy = view_dirs[3*i+1], vz = view_dirs[3*i+2];
    float px = xyz[3*i+0],       py = xyz[3*i+1],       pz = xyz[3*i+2];
    float sl0 = scale_log[3*i+0], sl1 = scale_log[3*i+1], sl2 = scale_log[3*i+2];
    float4 q  = rot_quat[i];
    float  ol = opacity_logit[i];
    float4 c0 = sh[3*i+0];
    float4 c1 = sh[3*i+1];
    float4 c2 = sh[3*i+2];

    // ---- opacity ----
    float opacity = sigmoidf(ol);

    // ---- rgb: degree-1 SH then sigmoid ----
    float r0 = C0*c0.x - C1*vy*c0.y + C1*vz*c0.z - C1*vx*c0.w;
    float r1 = C0*c1.x - C1*vy*c1.y + C1*vz*c1.z - C1*vx*c1.w;
    float r2 = C0*c2.x - C1*vy*c2.y + C1*vz*c2.z - C1*vx*c2.w;
    r0 = sigmoidf(r0); r1 = sigmoidf(r1); r2 = sigmoidf(r2);

    // ---- rotation from normalized quaternion ----
    float nrm = sqrtf(q.x*q.x + q.y*q.y + q.z*q.z + q.w*q.w);
    float inv = 1.0f / fmaxf(nrm, 1e-12f);
    float r = q.x*inv, x = q.y*inv, y = q.z*inv, z = q.w*inv;

    float R00 = 1.0f - 2.0f*(y*y + z*z);
    float R01 = 2.0f*(x*y - r*z);
    float R02 = 2.0f*(x*z + r*y);
    float R10 = 2.0f*(x*y + r*z);
    float R11 = 1.0f - 2.0f*(x*x + z*z);
    float R12 = 2.0f*(y*z - r*x);
    float R20 = 2.0f*(x*z - r*y);
    float R21 = 2.0f*(y*z + r*x);
    float R22 = 1.0f - 2.0f*(x*x + y*y);

    // ---- M = R * diag(scale) ; cov = M * M^T ----
    float s0 = expf(sl0), s1 = expf(sl1), s2 = expf(sl2);

    float M00 = R00*s0, M01 = R01*s1, M02 = R02*s2;
    float M10 = R10*s0, M11 = R11*s1, M12 = R12*s2;
    float M20 = R20*s0, M21 = R21*s1, M22 = R22*s2;

    float cv00 = M00*M00 + M01*M01 + M02*M02;
    float cv01 = M00*M10 + M01*M11 + M02*M12;
    float cv02 = M00*M20 + M01*M21 + M02*M22;
    float cv11 = M10*M10 + M11*M11 + M12*M12;
    float cv12 = M10*M20 + M11*M21 + M12*M22;
    float cv22 = M20*M20 + M21*M21 + M22*M22;

    // ---- stores ----
    out_xyz[3*i+0] = px; out_xyz[3*i+1] = py; out_xyz[3*i+2] = pz;

    float* cp = out_cov + 9*i;
    cp[0] = cv00; cp[1] = cv01; cp[2] = cv02;
    cp[3] = cv01; cp[4] = cv11; cp[5] = cv12;
    cp[6] = cv02; cp[7] = cv12; cp[8] = cv22;

    out_rgb[3*i+0] = r0; out_rgb[3*i+1] = r1; out_rgb[3*i+2] = r2;
    out_op[i] = opacity;
}

extern "C" void kernel_launch(void* const* d_in, const int* in_sizes, int n_in,
                              void* d_out, int out_size, void* d_ws, size_t ws_size,
                              hipStream_t stream) {
    const float*  view_dirs     = (const float*)d_in[0];
    const float*  xyz           = (const float*)d_in[1];
    const float*  scale_log     = (const float*)d_in[2];
    const float4* rot_quat      = (const float4*)d_in[3];
    const float*  opacity_logit = (const float*)d_in[4];
    const float4* sh            = (const float4*)d_in[5];

    int N = in_sizes[4];  // opacity_logit has N elements

    float* out = (float*)d_out;
    float* out_xyz = out;               // N*3
    float* out_cov = out + (size_t)3*N; // N*9
    float* out_rgb = out + (size_t)12*N;// N*3
    float* out_op  = out + (size_t)15*N;// N

    int block = 256;
    int grid = (N + block - 1) / block;
    gauss_kernel<<<grid, block, 0, stream>>>(view_dirs, xyz, scale_log, rot_quat,
                                             opacity_logit, sh,
                                             out_xyz, out_cov, out_rgb, out_op, N);
}